// Round 10
// baseline (316.099 us; speedup 1.0000x reference)
//
#include <hip/hip_runtime.h>
#include <cstdint>
#include <climits>

// Binarized 4-layer MLP via exact int8 MFMA (i32 accum) on gfx950.
// Round-10: ALL FOUR LAYERS FUSED into one kernel. Block = 32-row panel;
// activations live entirely in LDS (2 x 32 KB ping-pong, swizzled i8);
// B streamed from pre-arranged Wf fragment chunks in L2 (r9-verified
// layout) into a register double-buffer. Zero barriers inside K-loops
// (A is read-only per layer); 4 __syncthreads total. Eliminates 6x32 MB
// of intermediate global traffic + 3 dispatch ramps that made rounds 4-9
// schedule-invariant at ~58 us/GEMM.

typedef __attribute__((ext_vector_type(4))) int i32x4_t;

__device__ __forceinline__ void gload_lds16(const void* g, void* l) {
  __builtin_amdgcn_global_load_lds(
      (const __attribute__((address_space(1))) unsigned int*)g,
      (__attribute__((address_space(3))) unsigned int*)l, 16, 0, 0);
}

__device__ __forceinline__ int pack4(const float4 v) {
  int b0 = v.x > 0.f ? 1 : (v.x < 0.f ? -1 : 0);
  int b1 = v.y > 0.f ? 1 : (v.y < 0.f ? -1 : 0);
  int b2 = v.z > 0.f ? 1 : (v.z < 0.f ? -1 : 0);
  int b3 = v.w > 0.f ? 1 : (v.w < 0.f ? -1 : 0);
  return (b0 & 0xff) | ((b1 & 0xff) << 8) | ((b2 & 0xff) << 16) | (b3 << 24);
}

// ============================ FAST PATH (i8 MFMA) ===========================

// One dispatch: all conversions + threshold prep.
//   [0, 32768):      x rows -> i8 A0 (stride 832, pad zeroed)
//   [32768, 35648):  W1/W2/W3 -> Wf1/2/3 (B-frag chunk order; r9-verified)
//   [35648, 35664):  W4 -> Wf4 (16 chunks of 1 KB; cols>=10 zero)
//   [35664, 35677):  integer thresholds (f64) + final affine params
// Wf layout: chunk c = kt*64 + cb is 1024 B; byte (l6, j) (l6=0..63, j=0..15)
//   = sign(W[cb*16 + (l6&15)][kt*64 + (l6>>4)*16 + j]), 0 beyond K.
__global__ __launch_bounds__(256) void prep_mega_kernel(
    const float* __restrict__ x, int8_t* __restrict__ A0,
    const float* __restrict__ W1f, const float* __restrict__ W2f,
    const float* __restrict__ W3f, const float* __restrict__ W4f,
    int8_t* __restrict__ Wf1, int8_t* __restrict__ Wf2,
    int8_t* __restrict__ Wf3, int8_t* __restrict__ Wf4,
    const float* b1, const float* g1, const float* be1, const float* m1, const float* v1,
    const float* b2, const float* g2, const float* be2, const float* m2, const float* v2,
    const float* b3, const float* g3, const float* be3, const float* m3, const float* v3,
    const float* b4, const float* g4, const float* be4, const float* m4, const float* v4,
    int* __restrict__ T1, int* __restrict__ T2, int* __restrict__ T3,
    int8_t* __restrict__ S1, int8_t* __restrict__ S2, int8_t* __restrict__ S3,
    float* __restrict__ sc4, float* __restrict__ of4) {
  const int b = blockIdx.x;
  const int t = threadIdx.x;
  if (b < 32768) {
    const int col = t * 4;
    if (col < 784) {
      int packed = pack4(*(const float4*)(x + (size_t)b * 784 + col));
      *(int*)(A0 + (size_t)b * 832 + col) = packed;
    } else if (col < 832) {
      *(int*)(A0 + (size_t)b * 832 + col) = 0;  // zero the K-pad
    }
  } else if (b < 35648) {
    // B-fragment-order weight conversion (unchanged from r9; verified)
    const int b2i = b - 32768;
    const float* Wf; int8_t* Wo; int Kreal, blk;
    if (b2i < 832)        { Wf = W1f; Wo = Wf1; Kreal = 784;  blk = b2i;        }
    else if (b2i < 1856)  { Wf = W2f; Wo = Wf2; Kreal = 1024; blk = b2i - 832;  }
    else                  { Wf = W3f; Wo = Wf3; Kreal = 1024; blk = b2i - 1856; }
    const int o = (blk * 256 + t) * 4;
    const int j  = o & 15;
    const int l6 = (o >> 4) & 63;
    const int cb = (o >> 10) & 63;
    const int kt = o >> 16;
    const int colw = cb * 16 + (l6 & 15);
    const int k = kt * 64 + ((l6 >> 4) << 4) + j;
    int packed = 0;
    if (k < Kreal)
      packed = pack4(*(const float4*)(Wf + (size_t)colw * Kreal + k));
    *(int*)(Wo + o) = packed;
  } else if (b < 35664) {
    // W4 -> Wf4: 16 chunks (kt) of 1 KB; same frag formula, cols>=10 zero
    const int o = ((b - 35648) * 256 + t) * 4;   // [0, 16384)
    const int j  = o & 15;
    const int l6 = (o >> 4) & 63;
    const int kt = o >> 10;
    const int colw = l6 & 15;
    const int k = kt * 64 + ((l6 >> 4) << 4) + j;
    int packed = 0;
    if (colw < 10)
      packed = pack4(*(const float4*)(W4f + (size_t)colw * 1024 + k));
    *(int*)(Wf4 + o) = packed;
  } else {
    const int pb = b - 35664;
    if (pb < 12) {
      const int layer = pb >> 2;
      const int n = (pb & 3) * 256 + t;
      const float *bb, *gg, *be, *me, *va; int* T; int8_t* S;
      if (layer == 0)      { bb = b1; gg = g1; be = be1; me = m1; va = v1; T = T1; S = S1; }
      else if (layer == 1) { bb = b2; gg = g2; be = be2; me = m2; va = v2; T = T2; S = S2; }
      else                 { bb = b3; gg = g3; be = be3; me = m3; va = v3; T = T3; S = S3; }
      double g = (double)gg[n];
      double rs = 1.0 / sqrt((double)va[n] + 1e-5);
      int th; int8_t s;
      if (g > 0.0) {
        double tv = (double)me[n] - (double)bb[n] - (double)be[n] / (g * rs);
        tv = fmin(fmax(tv, -2.0e9), 2.0e9);
        th = (int)floor(tv) + 1; s = 1;
      } else if (g < 0.0) {
        double tv = (double)me[n] - (double)bb[n] - (double)be[n] / (g * rs);
        tv = fmin(fmax(tv, -2.0e9), 2.0e9);
        th = (int)ceil(tv); s = -1;
      } else {
        th = INT_MIN; s = (be[n] > 0.f) ? (int8_t)1 : (int8_t)-1;
      }
      T[n] = th; S[n] = s;
    } else if (t < 10) {
      double rs = 1.0 / sqrt((double)v4[t] + 1e-5);
      double sd = (double)g4[t] * rs;
      sc4[t] = (float)sd;
      of4[t] = (float)(sd * ((double)b4[t] - (double)m4[t]) + (double)be4[t]);
    }
  }
}

// One layer of the fused kernel: 32-row panel x 1024 cols, K<=1024.
// A in LDS [32][1024] i8, 16B-slot XOR swizzle: byte(row,k) = row*1024 +
// (k&~63) + ((((k>>4)&3) ^ ((row>>1)&3))<<4) + (k&15). B from Wf chunks in
// L2 (reg dbuf, vmcnt(4)). Wave wn covers cols [p*256+wn*64, +64) per pass
// p=0..3; wave tile 32x64 = 2x4 frags of mfma_i32_16x16x64_i8. NO barriers:
// lin is read-only for the whole layer; lout bytes are disjoint per thread.
__device__ __forceinline__ void do_layer(
    const int8_t* lin, int8_t* lout, int nkt,
    const int8_t* __restrict__ Wf,
    const int* __restrict__ T, const int8_t* __restrict__ S,
    int lane, int wn) {
  for (int p = 0; p < 4; ++p) {
    int a_off[2];
#pragma unroll
    for (int m = 0; m < 2; ++m) {
      const int row = m * 16 + (lane & 15);
      a_off[m] = row * 1024 + ((((lane >> 4) ^ (row >> 1)) & 3) << 4);
    }
    const int8_t* bq = Wf + ((size_t)(p * 16 + wn * 4)) * 1024 + lane * 16;
    i32x4_t acc[2][4];
#pragma unroll
    for (int m = 0; m < 2; ++m)
#pragma unroll
      for (int n = 0; n < 4; ++n) acc[m][n] = (i32x4_t){0, 0, 0, 0};
    i32x4_t bvA[4], bvB[4];
#pragma unroll
    for (int n = 0; n < 4; ++n) bvA[n] = *(const i32x4_t*)(bq + n * 1024);

#define FSTEP(KT, BVC, BVN)                                                   \
    {                                                                         \
      const int kt_ = (KT);                                                   \
      if (kt_ + 1 < nkt) {                                                    \
        _Pragma("unroll")                                                     \
        for (int n = 0; n < 4; ++n)                                           \
          BVN[n] = *(const i32x4_t*)(bq + (size_t)(kt_ + 1) * 65536 + n * 1024); \
        asm volatile("s_waitcnt vmcnt(4)" ::: "memory");                      \
      } else {                                                                \
        asm volatile("s_waitcnt vmcnt(0)" ::: "memory");                      \
      }                                                                       \
      i32x4_t av[2];                                                          \
      _Pragma("unroll")                                                       \
      for (int m = 0; m < 2; ++m)                                             \
        av[m] = *(const i32x4_t*)(lin + a_off[m] + kt_ * 64);                 \
      _Pragma("unroll")                                                       \
      for (int m = 0; m < 2; ++m)                                             \
        _Pragma("unroll")                                                     \
        for (int n = 0; n < 4; ++n)                                           \
          acc[m][n] = __builtin_amdgcn_mfma_i32_16x16x64_i8(av[m], BVC[n], acc[m][n], 0, 0, 0); \
    }

    int kt = 0;
    for (; kt + 2 <= nkt; kt += 2) { FSTEP(kt, bvA, bvB); FSTEP(kt + 1, bvB, bvA); }
    if (kt < nkt) FSTEP(kt, bvA, bvB);   // odd-nkt tail (after even #swaps)
#undef FSTEP

    // threshold epilogue -> swizzled i8 bytes into lout
    // write slot = n ^ ((row>>1)&3); read side uses ((k>>4)&3) ^ sw with
    // (k>>4)&3 == n for k = p*256+wn*64+n*16+.. -> consistent.
#pragma unroll
    for (int n = 0; n < 4; ++n) {
      const int oc = p * 256 + wn * 64 + n * 16 + (lane & 15);
      const int tn = T[oc];
      const int8_t snn = S[oc];
#pragma unroll
      for (int m = 0; m < 2; ++m)
#pragma unroll
        for (int r = 0; r < 4; ++r) {
          const int row = m * 16 + ((lane >> 4) << 2) + r;
          const int slot = (n ^ (row >> 1)) & 3;
          lout[row * 1024 + p * 256 + wn * 64 + (slot << 4) + (lane & 15)] =
              (acc[m][n][r] >= tn) ? snn : (int8_t)(-snn);
        }
    }
  }
}

// Fused 4-layer kernel. Grid 1024 blocks (32 rows each), 256 thr / 4 waves,
// 64 KB static LDS -> 2 blocks/CU (cross-block overlap). Panel staged once
// via gload_lds with pre-swizzled source; then 3 barrier-free layer GEMMs +
// the 10-col affine layer.
__global__ __launch_bounds__(256, 2) void fused_mlp_kernel(
    const int8_t* __restrict__ A0,
    const int8_t* __restrict__ Wf1, const int8_t* __restrict__ Wf2,
    const int8_t* __restrict__ Wf3, const int8_t* __restrict__ Wf4,
    const int* __restrict__ T1, const int8_t* __restrict__ S1,
    const int* __restrict__ T2, const int8_t* __restrict__ S2,
    const int* __restrict__ T3, const int8_t* __restrict__ S3,
    const float* __restrict__ sc4, const float* __restrict__ of4,
    float* __restrict__ out) {
  __shared__ int8_t smf[65536];          // buf0 [0,32K), buf1 [32K,64K)
  int8_t* buf0 = smf;
  int8_t* buf1 = smf + 32768;
  const int tid = threadIdx.x;
  const int lane = tid & 63;
  const int wn = tid >> 6;
  const int row0 = blockIdx.x * 32;

  // stage 32-row input panel into buf0 ([32][1024] swizzled; k>=832 garbage,
  // never read since layer-1 nkt=13). dst is linear per wave (g*16);
  // source carries the inverse swizzle (involution).
#pragma unroll
  for (int i = 0; i < 8; ++i) {
    const int g = tid + 256 * i;         // granule 0..2047
    const int row = g >> 6;
    const int sw = (row >> 1) & 3;
    const int sp = g & 3;
    const int k64 = (g >> 2) & 15;
    const int8_t* src = A0 + (size_t)(row0 + row) * 832 + k64 * 64 + (((sp ^ sw) & 3) << 4);
    gload_lds16(src, smf + g * 16);
  }
  __syncthreads();

  do_layer(buf0, buf1, 13, Wf1, T1, S1, lane, wn);
  __syncthreads();
  do_layer(buf1, buf0, 16, Wf2, T2, S2, lane, wn);
  __syncthreads();
  do_layer(buf0, buf1, 16, Wf3, T3, S3, lane, wn);
  __syncthreads();

  // layer 4: waves 0,1 each compute 16 rows x cols 0..15 (10 live), affine
  if (wn < 2) {
    const int row = wn * 16 + (lane & 15);
    const int a4 = row * 1024 + ((((lane >> 4) ^ (row >> 1)) & 3) << 4);
    i32x4_t acc4 = (i32x4_t){0, 0, 0, 0};
    const int8_t* bq = Wf4 + lane * 16;
#pragma unroll
    for (int kt = 0; kt < 16; ++kt) {
      i32x4_t bv = *(const i32x4_t*)(bq + kt * 1024);
      i32x4_t av = *(const i32x4_t*)(buf1 + a4 + kt * 64);
      acc4 = __builtin_amdgcn_mfma_i32_16x16x64_i8(av, bv, acc4, 0, 0, 0);
    }
    const int col = lane & 15;
    if (col < 10) {
      const float sc = sc4[col], of = of4[col];
#pragma unroll
      for (int r = 0; r < 4; ++r) {
        const int orow = wn * 16 + ((lane >> 4) << 2) + r;
        out[(size_t)(row0 + orow) * 10 + col] = sc * (float)acc4[r] + of;
      }
    }
  }
}

// ===================== FALLBACK PATH (round-1 popcount) =====================

#define A0_STRIDE 28

__global__ __launch_bounds__(256) void pack_w_kernel(
    const float* __restrict__ W, uint32_t* __restrict__ Wp,
    int nout, int K, int wstride) {
  int idx = blockIdx.x * blockDim.x + threadIdx.x;
  if (idx >= nout * wstride) return;
  int n = idx / wstride;
  int wi = idx - n * wstride;
  const float* wr = W + (size_t)n * K;
  uint32_t word = 0;
  int base = wi * 32;
  for (int i = 0; i < 32; ++i) {
    int c = base + i;
    if (c < K && wr[c] > 0.f) word |= (1u << i);
  }
  Wp[idx] = word;
}

__global__ __launch_bounds__(256) void prep_thr_kernel(
    const float* __restrict__ b, const float* __restrict__ gamma,
    const float* __restrict__ beta, const float* __restrict__ mean,
    const float* __restrict__ var, int K, int N,
    int* __restrict__ thr, uint32_t* __restrict__ flipm) {
  int n = blockIdx.x * blockDim.x + threadIdx.x;
  if (n >= N) return;
  double g = (double)gamma[n];
  double rs = 1.0 / sqrt((double)var[n] + 1e-5);
  int th;
  if (g != 0.0) {
    double t = (double)mean[n] - (double)b[n] - (double)beta[n] / (g * rs);
    double pt = ((double)K - t) * 0.5;
    th = (g > 0.0) ? (int)ceil(pt) : ((int)floor(pt) + 1);
  } else {
    th = (beta[n] > 0.f) ? (K + 2) : -1;
  }
  thr[n] = th;
  if ((n & 31) == 0) {
    uint32_t m = 0;
    for (int i = 0; i < 32 && (n + i) < N; ++i)
      if (gamma[n + i] < 0.f) m |= (1u << i);
    flipm[n >> 5] = m;
  }
}

__global__ __launch_bounds__(64) void prep_out_kernel(
    const float* __restrict__ b, const float* __restrict__ gamma,
    const float* __restrict__ beta, const float* __restrict__ mean,
    const float* __restrict__ var, int N,
    float* __restrict__ s, float* __restrict__ o) {
  int n = threadIdx.x;
  if (n >= N) return;
  double rs = 1.0 / sqrt((double)var[n] + 1e-5);
  double sd = (double)gamma[n] * rs;
  s[n] = (float)sd;
  o[n] = (float)(sd * ((double)b[n] - (double)mean[n]) + (double)beta[n]);
}

__global__ __launch_bounds__(256) void pack_a_kernel(
    const float* __restrict__ x, uint32_t* __restrict__ A0) {
  int gt = blockIdx.x * blockDim.x + threadIdx.x;
  int wv = gt >> 6;
  int lane = gt & 63;
  int row = wv / 13;
  int seg = wv - row * 13;
  int col = (seg << 6) + lane;
  bool pred = (col < 784) && (x[(size_t)row * 784 + col] > 0.f);
  unsigned long long m = __ballot(pred);
  int widx = seg * 2;
  if (lane == 0)
    A0[(size_t)row * A0_STRIDE + widx] = (uint32_t)m;
  else if (lane == 1 && widx + 1 < 25)
    A0[(size_t)row * A0_STRIDE + widx + 1] = (uint32_t)(m >> 32);
}

__device__ __forceinline__ void layer1024(
    uint32_t a[32], const uint32_t* __restrict__ Wp,
    const int* __restrict__ thr, const uint32_t* __restrict__ fm,
    uint32_t* lds, int lane, int w) {
  const int nb = w * 128;
  uint32_t word = 0;
#pragma unroll 2
  for (int ni = 0; ni < 128; ++ni) {
    const int n = nb + ni;
    const uint32_t* __restrict__ wp = Wp + n * 32;
    uint32_t p0 = 0, p1 = 0, p2 = 0, p3 = 0;
#pragma unroll
    for (int k = 0; k < 32; k += 4) {
      p0 += __popc(a[k + 0] ^ wp[k + 0]);
      p1 += __popc(a[k + 1] ^ wp[k + 1]);
      p2 += __popc(a[k + 2] ^ wp[k + 2]);
      p3 += __popc(a[k + 3] ^ wp[k + 3]);
    }
    int p = (int)(p0 + p1 + p2 + p3);
    word |= ((p < thr[n]) ? 1u : 0u) << (ni & 31);
    if ((ni & 31) == 31) {
      lds[lane * 33 + (n >> 5)] = word ^ fm[n >> 5];
      word = 0;
    }
  }
  __syncthreads();
#pragma unroll
  for (int k = 0; k < 32; ++k) a[k] = lds[lane * 33 + k];
  __syncthreads();
}

__global__ __launch_bounds__(512, 4) void fused_kernel(
    const uint32_t* __restrict__ A0,
    const uint32_t* __restrict__ Wp1, const int* __restrict__ thr1, const uint32_t* __restrict__ fm1,
    const uint32_t* __restrict__ Wp2, const int* __restrict__ thr2, const uint32_t* __restrict__ fm2,
    const uint32_t* __restrict__ Wp3, const int* __restrict__ thr3, const uint32_t* __restrict__ fm3,
    const uint32_t* __restrict__ Wp4, const float* __restrict__ s4, const float* __restrict__ o4,
    float* __restrict__ out) {
  __shared__ uint32_t lds[64 * 33];
  const int lane = threadIdx.x & 63;
  const int w = __builtin_amdgcn_readfirstlane((int)(threadIdx.x >> 6));
  const int row = blockIdx.x * 64 + lane;

  uint32_t a[32];
  {
    const uint4* A4 = (const uint4*)(A0 + (size_t)row * A0_STRIDE);
#pragma unroll
    for (int i = 0; i < 7; ++i) {
      uint4 q = A4[i];
      a[4 * i + 0] = q.x; a[4 * i + 1] = q.y; a[4 * i + 2] = q.z; a[4 * i + 3] = q.w;
    }
  }
  {
    const int nb = w * 128;
    uint32_t word = 0;
#pragma unroll 2
    for (int ni = 0; ni < 128; ++ni) {
      const int n = nb + ni;
      const uint32_t* __restrict__ wp = Wp1 + n * A0_STRIDE;
      uint32_t p0 = 0, p1 = 0, p2 = 0, p3 = 0;
#pragma unroll
      for (int k = 0; k < 24; k += 4) {
        p0 += __popc(a[k + 0] ^ wp[k + 0]);
        p1 += __popc(a[k + 1] ^ wp[k + 1]);
        p2 += __popc(a[k + 2] ^ wp[k + 2]);
        p3 += __popc(a[k + 3] ^ wp[k + 3]);
      }
      p0 += __popc(a[24] ^ wp[24]);
      int p = (int)(p0 + p1 + p2 + p3);
      word |= ((p < thr1[n]) ? 1u : 0u) << (ni & 31);
      if ((ni & 31) == 31) {
        lds[lane * 33 + (n >> 5)] = word ^ fm1[n >> 5];
        word = 0;
      }
    }
    __syncthreads();
#pragma unroll
    for (int k = 0; k < 32; ++k) a[k] = lds[lane * 33 + k];
    __syncthreads();
  }
  layer1024(a, Wp2, thr2, fm2, lds, lane, w);
  layer1024(a, Wp3, thr3, fm3, lds, lane, w);
  for (int j = w; j < 10; j += 8) {
    const uint32_t* __restrict__ wp = Wp4 + j * 32;
    uint32_t p0 = 0, p1 = 0, p2 = 0, p3 = 0;
#pragma unroll
    for (int k = 0; k < 32; k += 4) {
      p0 += __popc(a[k + 0] ^ wp[k + 0]);
      p1 += __popc(a[k + 1] ^ wp[k + 1]);
      p2 += __popc(a[k + 2] ^ wp[k + 2]);
      p3 += __popc(a[k + 3] ^ wp[k + 3]);
    }
    float dotf = 1024.f - 2.f * (float)(p0 + p1 + p2 + p3);
    out[(size_t)row * 10 + j] = s4[j] * dotf + o4[j];
  }
}

// ---------------------------------------------------------------------------
extern "C" void kernel_launch(void* const* d_in, const int* in_sizes, int n_in,
                              void* d_out, int out_size, void* d_ws, size_t ws_size,
                              hipStream_t stream) {
  const float* x   = (const float*)d_in[0];
  const float* W1  = (const float*)d_in[1];
  const float* b1  = (const float*)d_in[2];
  const float* g1  = (const float*)d_in[3];
  const float* be1 = (const float*)d_in[4];
  const float* m1  = (const float*)d_in[5];
  const float* v1  = (const float*)d_in[6];
  const float* W2  = (const float*)d_in[7];
  const float* b2  = (const float*)d_in[8];
  const float* g2  = (const float*)d_in[9];
  const float* be2 = (const float*)d_in[10];
  const float* m2  = (const float*)d_in[11];
  const float* v2  = (const float*)d_in[12];
  const float* W3  = (const float*)d_in[13];
  const float* b3  = (const float*)d_in[14];
  const float* g3  = (const float*)d_in[15];
  const float* be3 = (const float*)d_in[16];
  const float* m3  = (const float*)d_in[17];
  const float* v3  = (const float*)d_in[18];
  const float* W4  = (const float*)d_in[19];
  const float* b4  = (const float*)d_in[20];
  const float* g4  = (const float*)d_in[21];
  const float* be4 = (const float*)d_in[22];
  const float* m4  = (const float*)d_in[23];
  const float* v4  = (const float*)d_in[24];
  float* outp = (float*)d_out;
  (void)in_sizes; (void)n_in; (void)out_size;

  uint8_t* ws = (uint8_t*)d_ws;
  const size_t NEED = 64ULL << 20;

  if (ws_size >= NEED) {
    size_t off = 0;
    int8_t* A0  = (int8_t*)(ws + off); off += (size_t)32768 * 832;          // 27.3 MB
    int8_t* Wf1 = (int8_t*)(ws + off); off += (size_t)13 * 64 * 1024;       // 832 KB
    int8_t* Wf2 = (int8_t*)(ws + off); off += (size_t)16 * 64 * 1024;       // 1 MB
    int8_t* Wf3 = (int8_t*)(ws + off); off += (size_t)16 * 64 * 1024;       // 1 MB
    int8_t* Wf4 = (int8_t*)(ws + off); off += 16384;
    int* T1     = (int*)(ws + off);    off += 4096;
    int* T2     = (int*)(ws + off);    off += 4096;
    int* T3     = (int*)(ws + off);    off += 4096;
    int8_t* S1  = (int8_t*)(ws + off); off += 1024;
    int8_t* S2  = (int8_t*)(ws + off); off += 1024;
    int8_t* S3  = (int8_t*)(ws + off); off += 1024;
    float* sc4  = (float*)(ws + off);  off += 512;
    float* of4  = (float*)(ws + off);  off += 512;

    prep_mega_kernel<<<35677, 256, 0, stream>>>(
        x, A0, W1, W2, W3, W4, Wf1, Wf2, Wf3, Wf4,
        b1, g1, be1, m1, v1, b2, g2, be2, m2, v2,
        b3, g3, be3, m3, v3, b4, g4, be4, m4, v4,
        T1, T2, T3, S1, S2, S3, sc4, of4);

    fused_mlp_kernel<<<1024, 256, 0, stream>>>(
        A0, Wf1, Wf2, Wf3, Wf4, T1, S1, T2, S2, T3, S3, sc4, of4, outp);
  } else {
    size_t off = 0;
    uint32_t* A0  = (uint32_t*)(ws + off); off += (size_t)32768 * A0_STRIDE * 4;
    uint32_t* Wp1 = (uint32_t*)(ws + off); off += (size_t)1024 * A0_STRIDE * 4;
    uint32_t* Wp2 = (uint32_t*)(ws + off); off += (size_t)1024 * 32 * 4;
    uint32_t* Wp3 = (uint32_t*)(ws + off); off += (size_t)1024 * 32 * 4;
    uint32_t* Wp4 = (uint32_t*)(ws + off); off += 4096;
    int* thr1     = (int*)(ws + off);      off += 4096;
    int* thr2     = (int*)(ws + off);      off += 4096;
    int* thr3     = (int*)(ws + off);      off += 4096;
    uint32_t* fm1 = (uint32_t*)(ws + off); off += 128;
    uint32_t* fm2 = (uint32_t*)(ws + off); off += 128;
    uint32_t* fm3 = (uint32_t*)(ws + off); off += 128;
    float* s4o    = (float*)(ws + off);    off += 64;
    float* o4o    = (float*)(ws + off);    off += 64;

    pack_w_kernel<<<(1024 * A0_STRIDE + 255) / 256, 256, 0, stream>>>(W1, Wp1, 1024, 784, A0_STRIDE);
    pack_w_kernel<<<(1024 * 32 + 255) / 256, 256, 0, stream>>>(W2, Wp2, 1024, 1024, 32);
    pack_w_kernel<<<(1024 * 32 + 255) / 256, 256, 0, stream>>>(W3, Wp3, 1024, 1024, 32);
    pack_w_kernel<<<(10 * 32 + 255) / 256, 256, 0, stream>>>(W4, Wp4, 10, 1024, 32);
    prep_thr_kernel<<<4, 256, 0, stream>>>(b1, g1, be1, m1, v1, 784, 1024, thr1, fm1);
    prep_thr_kernel<<<4, 256, 0, stream>>>(b2, g2, be2, m2, v2, 1024, 1024, thr2, fm2);
    prep_thr_kernel<<<4, 256, 0, stream>>>(b3, g3, be3, m3, v3, 1024, 1024, thr3, fm3);
    prep_out_kernel<<<1, 64, 0, stream>>>(b4, g4, be4, m4, v4, 10, s4o, o4o);
    pack_a_kernel<<<(32768 * 13) / 4, 256, 0, stream>>>(x, A0);
    fused_kernel<<<512, 512, 0, stream>>>(A0, Wp1, thr1, fm1, Wp2, thr2, fm2,
                                          Wp3, thr3, fm3, Wp4, s4o, o4o, outp);
  }
}